// Round 11
// baseline (4387.747 us; speedup 1.0000x reference)
//
#include <hip/hip_runtime.h>
#include <hip/hip_bf16.h>
#include <math.h>

#define BB 64
#define NPIX 196
#define ENCD 2048
#define DECD 512
#define VOCAB_N 10000
#define MAXLEN 52
#define TT 51
#define NPADFC 10048

// Output layout (floats): preds | captions | declens | alphas
#define PRED_SZ   (BB * TT * VOCAB_N)
#define CAPS_SZ   (BB * MAXLEN)
#define LENS_SZ   (BB)
#define ALPHAS_OFF (PRED_SZ + CAPS_SZ + LENS_SZ)

typedef __attribute__((ext_vector_type(8))) short short8;
typedef __attribute__((ext_vector_type(4))) short short4v;
typedef __attribute__((ext_vector_type(4))) float f32x4;

__device__ __forceinline__ float fsigm(float x) {
    return 1.0f / (1.0f + __expf(-x));
}
__device__ __forceinline__ float ftanh(float x) {
    x = fminf(fmaxf(x, -15.0f), 15.0f);
    float e = __expf(2.0f * x);
    return (e - 1.0f) / (e + 1.0f);
}
__device__ __forceinline__ float bf2f(unsigned short u) {
    union { unsigned int i; float f; } v;
    v.i = ((unsigned int)u) << 16;
    return v.f;
}
__device__ __forceinline__ unsigned short f2bf(float f) {
    union { float f; unsigned int i; } v;
    v.f = f;
    unsigned int r = v.i + 0x7FFFu + ((v.i >> 16) & 1u);
    return (unsigned short)(r >> 16);
}

// ---------------------------------------------------------------------------
// Generic MFMA GEMM (verified). Used for the setup inithc GEMM.
// ---------------------------------------------------------------------------
__global__ __launch_bounds__(256) void gemm_mfma(
    const unsigned short* __restrict__ A, int lda,
    const unsigned short* __restrict__ Wp, int Npad,
    int nkb, long slice_stride,
    float* __restrict__ C, unsigned short* __restrict__ C16, long ldc,
    const float* __restrict__ bias, int N, int act,
    const int* __restrict__ caplen, int t)
{
    const int n0 = blockIdx.x * 64;
    const int m0 = blockIdx.y * 64;
    const int kz = blockIdx.z;
    A  += (size_t)kz * nkb * 32;
    Wp += (size_t)kz * nkb * Npad * 32;
    if (C) C += (size_t)kz * slice_stride;

    const int w  = threadIdx.x >> 6;
    const int l  = threadIdx.x & 63;
    const int lr = l & 15;
    const int q  = l >> 4;

    const unsigned short* ap = A + (size_t)(m0 + 16 * w + lr) * lda + q * 8;
    const unsigned short* bp = Wp + (size_t)(n0 + lr) * 32 + q * 8;
    const size_t bstep = (size_t)Npad * 32;

    f32x4 acc[4];
#pragma unroll
    for (int i = 0; i < 4; ++i) acc[i] = (f32x4){0.f, 0.f, 0.f, 0.f};

    short8 a  = *(const short8*)ap;
    short8 b0 = *(const short8*)(bp);
    short8 b1 = *(const short8*)(bp + 512);
    short8 b2 = *(const short8*)(bp + 1024);
    short8 b3 = *(const short8*)(bp + 1536);

    for (int kb = 0; kb < nkb; ++kb) {
        const size_t nxt = (kb + 1 < nkb) ? 1 : 0;
        const unsigned short* apn = ap + nxt * 32;
        const unsigned short* bpn = bp + nxt * bstep;
        short8 an  = *(const short8*)apn;
        short8 bn0 = *(const short8*)(bpn);
        short8 bn1 = *(const short8*)(bpn + 512);
        short8 bn2 = *(const short8*)(bpn + 1024);
        short8 bn3 = *(const short8*)(bpn + 1536);
        acc[0] = __builtin_amdgcn_mfma_f32_16x16x32_bf16(a, b0, acc[0], 0, 0, 0);
        acc[1] = __builtin_amdgcn_mfma_f32_16x16x32_bf16(a, b1, acc[1], 0, 0, 0);
        acc[2] = __builtin_amdgcn_mfma_f32_16x16x32_bf16(a, b2, acc[2], 0, 0, 0);
        acc[3] = __builtin_amdgcn_mfma_f32_16x16x32_bf16(a, b3, acc[3], 0, 0, 0);
        a = an; b0 = bn0; b1 = bn1; b2 = bn2; b3 = bn3;
        ap = apn; bp = bpn;
    }

    const int r0 = q * 4;
#pragma unroll
    for (int cf = 0; cf < 4; ++cf) {
        int col = n0 + cf * 16 + lr;
        if (col >= N) continue;
        float bv = bias ? bias[col] : 0.f;
#pragma unroll
        for (int r = 0; r < 4; ++r) {
            int row = m0 + 16 * w + r0 + r;
            float v = acc[cf][r] + bv;
            if (act == 1 || (act == 2 && col < 2048)) v = fsigm(v);
            if (caplen) v *= (t < caplen[row] - 1) ? 1.f : 0.f;
            if (C16) C16[(size_t)row * ldc + col] = f2bf(v);
            else     C [(size_t)row * ldc + col] = v;
        }
    }
}

// ---------------------------------------------------------------------------
// FUSED gadec + attention step kernel. 168 blocks x 512 threads.
//  blocks 0..39  (4 waves active): gadec = [sigmoid(h@Wfbeta+b)|h@Wd+bd]
//     (the verified gemm_mfma 40-block path), then flag++ (device scope).
//  blocks 40..167: attawe (b = (bx-40)&63, dh = (bx-40)>>6). Pre-loads Wf
//     and does the emb gather, then acquire-spins on flag==40 before
//     reading gadec. Same math as the round-10 attawe.
// All 168 blocks are co-resident (<=256 CUs) and producers are dispatched
// first, so the spin is short and deadlock-free.
// ---------------------------------------------------------------------------
__global__ __launch_bounds__(512) void fusedstep_kernel(
    const unsigned short* __restrict__ hT,     // hh[t]
    const unsigned short* __restrict__ WpG,
    const float* __restrict__ bcat,
    float* __restrict__ gadec,
    const unsigned short* __restrict__ attenc16,
    const unsigned short* __restrict__ enc16,
    const float* __restrict__ Wf, const float* __restrict__ bf_,
    const float* __restrict__ emb, const int* __restrict__ caps,
    const int* __restrict__ caplen, int t,
    unsigned short* __restrict__ xcatEG,
    float* __restrict__ alphas_out,
    int* __restrict__ flag)
{
    const int bx = blockIdx.x;
    const int tid = threadIdx.x;

    if (bx < 40) {
        // ---- gadec producer (verified gemm path, waves 0..3) ----
        if (tid < 256) {
            const int n0 = bx * 64;
            const int w  = tid >> 6;
            const int l  = tid & 63;
            const int lr = l & 15;
            const int q  = l >> 4;

            const unsigned short* ap = hT + (size_t)(16 * w + lr) * 512 + q * 8;
            const unsigned short* bp = WpG + (size_t)(n0 + lr) * 32 + q * 8;
            const size_t bstep = (size_t)2560 * 32;

            f32x4 acc[4];
#pragma unroll
            for (int i = 0; i < 4; ++i) acc[i] = (f32x4){0.f, 0.f, 0.f, 0.f};

            short8 a  = *(const short8*)ap;
            short8 b0 = *(const short8*)(bp);
            short8 b1 = *(const short8*)(bp + 512);
            short8 b2 = *(const short8*)(bp + 1024);
            short8 b3 = *(const short8*)(bp + 1536);

            for (int kb = 0; kb < 16; ++kb) {
                const size_t nxt = (kb + 1 < 16) ? 1 : 0;
                const unsigned short* apn = ap + nxt * 32;
                const unsigned short* bpn = bp + nxt * bstep;
                short8 an  = *(const short8*)apn;
                short8 bn0 = *(const short8*)(bpn);
                short8 bn1 = *(const short8*)(bpn + 512);
                short8 bn2 = *(const short8*)(bpn + 1024);
                short8 bn3 = *(const short8*)(bpn + 1536);
                acc[0] = __builtin_amdgcn_mfma_f32_16x16x32_bf16(a, b0, acc[0], 0, 0, 0);
                acc[1] = __builtin_amdgcn_mfma_f32_16x16x32_bf16(a, b1, acc[1], 0, 0, 0);
                acc[2] = __builtin_amdgcn_mfma_f32_16x16x32_bf16(a, b2, acc[2], 0, 0, 0);
                acc[3] = __builtin_amdgcn_mfma_f32_16x16x32_bf16(a, b3, acc[3], 0, 0, 0);
                a = an; b0 = bn0; b1 = bn1; b2 = bn2; b3 = bn3;
                ap = apn; bp = bpn;
            }

            const int r0 = q * 4;
#pragma unroll
            for (int cf = 0; cf < 4; ++cf) {
                int col = n0 + cf * 16 + lr;
                float bv = bcat[col];
#pragma unroll
                for (int r = 0; r < 4; ++r) {
                    int row = 16 * w + r0 + r;
                    float v = acc[cf][r] + bv;
                    if (col < 2048) v = fsigm(v);
                    gadec[(size_t)row * 2560 + col] = v;
                }
            }
        }
        __syncthreads();
        if (tid == 0) {
            __threadfence();
            atomicAdd(flag, 1);
        }
        return;
    }

    // ---- attawe consumer ----
    const int cb = bx - 40;
    const int b  = cb & 63;
    const int dh = cb >> 6;
    const int lane = tid & 63, wid = tid >> 6;
    __shared__ float av[512];
    __shared__ float wv[512];
    __shared__ float es[NPIX];
    __shared__ float alpha_s[NPIX];
    __shared__ float r8[8];
    __shared__ float smax, ssum;

    wv[tid] = Wf[tid];
    unsigned short* xr = xcatEG + (size_t)b * 2560;
    if (dh == 0) {
        int wword = caps[b * MAXLEN + t];
        xr[tid] = f2bf(emb[(size_t)wword * 512 + tid]);
    }

    if (tid == 0) {
        while (__hip_atomic_load(flag, __ATOMIC_ACQUIRE, __HIP_MEMORY_SCOPE_AGENT) < 40) {
            __builtin_amdgcn_s_sleep(1);
        }
        __threadfence();
    }
    __syncthreads();

    av[tid] = gadec[(size_t)b * 2560 + 2048 + tid];
    __syncthreads();

    float mya[8], myw[8];
#pragma unroll
    for (int i = 0; i < 8; ++i) {
        mya[i] = av[lane * 8 + i];
        myw[i] = wv[lane * 8 + i];
    }

    float bf0 = bf_[0];
    for (int p = wid; p < NPIX; p += 8) {
        const unsigned short* ae = attenc16 + ((size_t)(b * NPIX + p)) * 512 + lane * 8;
        short8 e8 = *(const short8*)ae;
        float s = 0.f;
#pragma unroll
        for (int i = 0; i < 8; ++i)
            s += ftanh(bf2f((unsigned short)e8[i]) + mya[i]) * myw[i];
        for (int off = 32; off; off >>= 1) s += __shfl_down(s, off);
        if (lane == 0) es[p] = s + bf0;
    }
    __syncthreads();

    float v = (tid < NPIX) ? es[tid] : -1e30f;
    float m = v;
    for (int off = 32; off; off >>= 1) m = fmaxf(m, __shfl_down(m, off));
    if (lane == 0) r8[wid] = m;
    __syncthreads();
    if (tid == 0) {
        float mm = r8[0];
#pragma unroll
        for (int i = 1; i < 8; ++i) mm = fmaxf(mm, r8[i]);
        smax = mm;
    }
    __syncthreads();

    float ev = (tid < NPIX) ? __expf(v - smax) : 0.0f;
    float s = ev;
    for (int off = 32; off; off >>= 1) s += __shfl_down(s, off);
    if (lane == 0) r8[wid] = s;
    __syncthreads();
    if (tid == 0) {
        float ss = 0.f;
#pragma unroll
        for (int i = 0; i < 8; ++i) ss += r8[i];
        ssum = ss;
    }
    __syncthreads();

    float mk = (t < caplen[b] - 1) ? 1.0f : 0.0f;
    if (tid < NPIX) {
        float a = ev / ssum;
        alpha_s[tid] = a;
        if (dh == 0)
            alphas_out[((size_t)b * TT + t) * NPIX + tid] = a * mk;
    }
    __syncthreads();

    // awe: this block's 1024-dim half, 2 dims per thread (4B loads)
    int d0 = dh * 1024 + tid * 2;
    const unsigned short* e = enc16 + (size_t)b * NPIX * ENCD + d0;
    float s0 = 0.f, s1 = 0.f;
    for (int p = 0; p < NPIX; ++p) {
        unsigned int vv = *(const unsigned int*)(e + (size_t)p * ENCD);
        float a = alpha_s[p];
        s0 += a * bf2f((unsigned short)(vv & 0xffffu));
        s1 += a * bf2f((unsigned short)(vv >> 16));
    }
    const float* gtt = gadec + (size_t)b * 2560 + d0;
    xr[512 + d0 + 0] = f2bf(s0 * gtt[0]);
    xr[512 + d0 + 1] = f2bf(s1 * gtt[1]);
}

// ---------------------------------------------------------------------------
// Fused gates GEMM + LSTM (verified). 128 blocks (4m x 32n) x 256 thr.
// ---------------------------------------------------------------------------
__global__ __launch_bounds__(256) void gateslstm_kernel(
    const unsigned short* __restrict__ xcatEG,   // [64][2560] emb|gate*awe
    const unsigned short* __restrict__ hprev,    // [64][512]
    const unsigned short* __restrict__ WpLi,
    const float* __restrict__ bsum,
    const int* __restrict__ caplen, int t,
    float* __restrict__ c,
    unsigned short* __restrict__ hnext)          // [64][512]
{
    __shared__ float gt[4][16][68];

    const int bx = blockIdx.x;
    const int nx = bx & 31;
    const int my = bx >> 5;
    const int m0 = my * 16;
    const int n0 = nx * 64;
    const int tid = threadIdx.x;
    const int ws = tid >> 6;       // wave = K-slice (768 each)
    const int l  = tid & 63;
    const int lr = l & 15;
    const int q  = l >> 4;

    const unsigned short* arow_x = xcatEG + (size_t)(m0 + lr) * 2560;
    const unsigned short* arow_h = hprev  + (size_t)(m0 + lr) * 512;
    const int kbase = ws * 768 + q * 8;

    const unsigned short* bp = WpLi + ((size_t)(ws * 24) * 2048 + n0 + lr) * 32 + q * 8;
    const size_t bstep = (size_t)2048 * 32;

    f32x4 acc[4];
#pragma unroll
    for (int i = 0; i < 4; ++i) acc[i] = (f32x4){0.f, 0.f, 0.f, 0.f};

#define ALOAD(kb) ({ int k0_ = kbase + (kb) * 32; \
    (k0_ < 2560) ? *(const short8*)(arow_x + k0_) \
                 : *(const short8*)(arow_h + (k0_ - 2560)); })

    short8 a  = ALOAD(0);
    short8 b0 = *(const short8*)(bp);
    short8 b1 = *(const short8*)(bp + 512);
    short8 b2 = *(const short8*)(bp + 1024);
    short8 b3 = *(const short8*)(bp + 1536);

    for (int kb = 0; kb < 24; ++kb) {
        const int kn = (kb + 1 < 24) ? kb + 1 : kb;
        const unsigned short* bpn = bp + ((kb + 1 < 24) ? bstep : 0);
        short8 an  = ALOAD(kn);
        short8 bn0 = *(const short8*)(bpn);
        short8 bn1 = *(const short8*)(bpn + 512);
        short8 bn2 = *(const short8*)(bpn + 1024);
        short8 bn3 = *(const short8*)(bpn + 1536);
        acc[0] = __builtin_amdgcn_mfma_f32_16x16x32_bf16(a, b0, acc[0], 0, 0, 0);
        acc[1] = __builtin_amdgcn_mfma_f32_16x16x32_bf16(a, b1, acc[1], 0, 0, 0);
        acc[2] = __builtin_amdgcn_mfma_f32_16x16x32_bf16(a, b2, acc[2], 0, 0, 0);
        acc[3] = __builtin_amdgcn_mfma_f32_16x16x32_bf16(a, b3, acc[3], 0, 0, 0);
        a = an; b0 = bn0; b1 = bn1; b2 = bn2; b3 = bn3;
        bp = bpn;
    }
#undef ALOAD

    const int r0 = q * 4;
#pragma unroll
    for (int cf = 0; cf < 4; ++cf)
#pragma unroll
        for (int r = 0; r < 4; ++r)
            gt[ws][r0 + r][cf * 16 + lr] = acc[cf][r];
    __syncthreads();

    // LSTM epilogue: 256 threads -> (row, unit) pairs, 16x16
    const int row = tid & 15;
    const int jj  = tid >> 4;
    const int b   = m0 + row;
    const int j   = nx * 16 + jj;
    const int lc  = 4 * jj;
    float gi = bsum[j],        gf = bsum[512 + j];
    float gg = bsum[1024 + j], go = bsum[1536 + j];
#pragma unroll
    for (int s = 0; s < 4; ++s) {
        gi += gt[s][row][lc + 0];
        gf += gt[s][row][lc + 1];
        gg += gt[s][row][lc + 2];
        go += gt[s][row][lc + 3];
    }
    const int cidx = b * 512 + j;
    float cn = fsigm(gf) * c[cidx] + fsigm(gi) * ftanh(gg);
    float hn = fsigm(go) * ftanh(cn);
    bool upd = (t < caplen[b] - 1);
    if (upd) c[cidx] = cn;
    hnext[cidx] = upd ? f2bf(hn) : hprev[cidx];
}

// ---------------------------------------------------------------------------
// Final preds GEMM over hh[1..TT]: rows = t*64+b (3264), K=512.
// Grid (160, 26): XCD-pinned n-tiles; 2 m-tiles/block (B-fragment reuse).
// Epilogue stages each 64x64 tile through LDS and stores float4 per lane:
// 16 lanes cover 64 consecutive cols = 256B contiguous per row.
// ---------------------------------------------------------------------------
__global__ __launch_bounds__(256) void preds_gemm(
    const unsigned short* __restrict__ hhist,   // = hh + 64*512
    const unsigned short* __restrict__ WpF,
    const float* __restrict__ bfc,
    const int* __restrict__ caplen,
    float* __restrict__ out)
{
    if (blockIdx.x >= 157) return;
    __shared__ float ot[64][68];
    const int n0 = blockIdx.x * 64;
    const int row0 = blockIdx.y * 128;
    const bool two = (row0 + 128 <= TT * BB);
    const int w  = threadIdx.x >> 6;
    const int l  = threadIdx.x & 63;
    const int lr = l & 15;
    const int q  = l >> 4;

    const unsigned short* ap0 = hhist + (size_t)(row0 + 16 * w + lr) * 512 + q * 8;
    const unsigned short* ap1 = ap0 + (size_t)64 * 512;
    const unsigned short* bp = WpF + (size_t)(n0 + lr) * 32 + q * 8;
    const size_t bstep = (size_t)NPADFC * 32;

    f32x4 acc[4], acc2[4];
#pragma unroll
    for (int i = 0; i < 4; ++i) {
        acc[i]  = (f32x4){0.f, 0.f, 0.f, 0.f};
        acc2[i] = (f32x4){0.f, 0.f, 0.f, 0.f};
    }

    short8 a0 = *(const short8*)ap0;
    short8 a1 = two ? *(const short8*)ap1 : a0;
    short8 b0 = *(const short8*)(bp);
    short8 b1 = *(const short8*)(bp + 512);
    short8 b2 = *(const short8*)(bp + 1024);
    short8 b3 = *(const short8*)(bp + 1536);

    for (int kb = 0; kb < 16; ++kb) {
        const size_t nxt = (kb + 1 < 16) ? 1 : 0;
        const unsigned short* apn0 = ap0 + nxt * 32;
        const unsigned short* apn1 = ap1 + nxt * 32;
        const unsigned short* bpn = bp + nxt * bstep;
        short8 an0 = *(const short8*)apn0;
        short8 an1 = two ? *(const short8*)apn1 : an0;
        short8 bn0 = *(const short8*)(bpn);
        short8 bn1 = *(const short8*)(bpn + 512);
        short8 bn2 = *(const short8*)(bpn + 1024);
        short8 bn3 = *(const short8*)(bpn + 1536);
        acc[0]  = __builtin_amdgcn_mfma_f32_16x16x32_bf16(a0, b0, acc[0], 0, 0, 0);
        acc[1]  = __builtin_amdgcn_mfma_f32_16x16x32_bf16(a0, b1, acc[1], 0, 0, 0);
        acc[2]  = __builtin_amdgcn_mfma_f32_16x16x32_bf16(a0, b2, acc[2], 0, 0, 0);
        acc[3]  = __builtin_amdgcn_mfma_f32_16x16x32_bf16(a0, b3, acc[3], 0, 0, 0);
        acc2[0] = __builtin_amdgcn_mfma_f32_16x16x32_bf16(a1, b0, acc2[0], 0, 0, 0);
        acc2[1] = __builtin_amdgcn_mfma_f32_16x16x32_bf16(a1, b1, acc2[1], 0, 0, 0);
        acc2[2] = __builtin_amdgcn_mfma_f32_16x16x32_bf16(a1, b2, acc2[2], 0, 0, 0);
        acc2[3] = __builtin_amdgcn_mfma_f32_16x16x32_bf16(a1, b3, acc2[3], 0, 0, 0);
        a0 = an0; a1 = an1; b0 = bn0; b1 = bn1; b2 = bn2; b3 = bn3;
        ap0 = apn0; ap1 = apn1; bp = bpn;
    }

    const int r0 = q * 4;
    const int colg = threadIdx.x & 15;   // 16 groups of 4 cols
    const int rowi = threadIdx.x >> 4;   // 16 rows per pass
    const int cbase = n0 + colg * 4;

#pragma unroll
    for (int mt = 0; mt < 2; ++mt) {
        if (mt == 1 && !two) break;
#pragma unroll
        for (int cf = 0; cf < 4; ++cf)
#pragma unroll
            for (int r = 0; r < 4; ++r)
                ot[16 * w + r0 + r][cf * 16 + lr] = mt ? acc2[cf][r] : acc[cf][r];
        __syncthreads();

#pragma unroll
        for (int ps = 0; ps < 4; ++ps) {
            int lrow = ps * 16 + rowi;
            int row = row0 + mt * 64 + lrow;
            int tt = row >> 6, b = row & 63;
            float mk = (tt < caplen[b] - 1) ? 1.f : 0.f;
            float4 v;
            v.x = (ot[lrow][colg * 4 + 0] + bfc[cbase + 0]) * mk;
            v.y = (ot[lrow][colg * 4 + 1] + bfc[cbase + 1]) * mk;
            v.z = (ot[lrow][colg * 4 + 2] + bfc[cbase + 2]) * mk;
            v.w = (ot[lrow][colg * 4 + 3] + bfc[cbase + 3]) * mk;
            float* o = out + ((size_t)b * TT + tt) * VOCAB_N + cbase;
            if (cbase + 3 < VOCAB_N) {
                *(float4*)o = v;
            } else {
                if (cbase + 0 < VOCAB_N) o[0] = v.x;
                if (cbase + 1 < VOCAB_N) o[1] = v.y;
                if (cbase + 2 < VOCAB_N) o[2] = v.z;
                if (cbase + 3 < VOCAB_N) o[3] = v.w;
            }
        }
        __syncthreads();
    }
}

// ---------------------------------------------------------------------------
// Weight packing: Wp[(kb*Npad + n)*32 + kk] = src[k=kb*32+kk][n], bf16.
// mode 0: single source; mode 1: n-concat [W1|W2].
// ---------------------------------------------------------------------------
__global__ void pack_kernel(const float* __restrict__ W1, const float* __restrict__ W2,
                            int N1, int N2, int K1, int Npad, int mode,
                            unsigned short* __restrict__ Wp, int total)
{
    int idx = blockIdx.x * 256 + threadIdx.x;
    if (idx >= total) return;
    int kk = idx & 31;
    int r  = idx >> 5;
    int n  = r % Npad;
    int kb = r / Npad;
    int k  = kb * 32 + kk;
    float v = 0.f;
    if (mode == 0) {
        if (n < N1) v = W1[(size_t)k * N1 + n];
    } else if (mode == 1) {
        v = (n < N1) ? W1[(size_t)k * N1 + n] : W2[(size_t)k * N2 + (n - N1)];
    } else {
        v = (k < K1) ? W1[(size_t)k * N1 + n] : W2[(size_t)(k - K1) * N1 + n];
    }
    Wp[idx] = f2bf(v);
}

// gate-interleaved pack of [W_ih(2560x2048); W_hh(512x2048)]:
// packed col n -> original col (n&3)*512 + (n>>2)   (verified round 3)
__global__ void packGi_kernel(const float* __restrict__ Wih,
                              const float* __restrict__ Whh,
                              unsigned short* __restrict__ Wp, int total)
{
    int idx = blockIdx.x * 256 + threadIdx.x;
    if (idx >= total) return;
    int kk = idx & 31;
    int r  = idx >> 5;
    int n  = r % 2048;
    int kb = r / 2048;
    int k  = kb * 32 + kk;
    int oc = (n & 3) * 512 + (n >> 2);
    float v = (k < 2560) ? Wih[(size_t)k * 2048 + oc]
                         : Whh[(size_t)(k - 2560) * 2048 + oc];
    Wp[idx] = f2bf(v);
}

__global__ void cast_kernel(const float* __restrict__ src,
                            unsigned short* __restrict__ dst, int n)
{
    int i = (blockIdx.x * 256 + threadIdx.x) * 4;
    if (i >= n) return;
    float4 v = *(const float4*)(src + i);
    dst[i]     = f2bf(v.x);
    dst[i + 1] = f2bf(v.y);
    dst[i + 2] = f2bf(v.z);
    dst[i + 3] = f2bf(v.w);
}

// bcat[2560] = [b_fbeta | b_dec_att]; bsum[2048] = b_ih + b_hh;
// bcatI[1024] = [b_init_h | b_init_c]; flags[64] = 0
__global__ void bias_prep(const float* __restrict__ bfb, const float* __restrict__ bda,
                          const float* __restrict__ bih, const float* __restrict__ bhh,
                          const float* __restrict__ bh, const float* __restrict__ bc,
                          float* __restrict__ bcat, float* __restrict__ bsum,
                          float* __restrict__ bcatI, int* __restrict__ flags)
{
    int i = blockIdx.x * 256 + threadIdx.x;
    if (i < 2048) { bcat[i] = bfb[i]; bsum[i] = bih[i] + bhh[i]; }
    else if (i < 2560) bcat[i] = bda[i - 2048];
    else if (i < 3072) bcatI[i - 2560] = bh[i - 2560];
    else if (i < 3584) bcatI[i - 2560] = bc[i - 3072];
    else if (i < 3648) flags[i - 3584] = 0;
}

// mean over pixels, from enc16 (bf16), fp32 accum, bf16 out
__global__ void mean_kernel(const unsigned short* __restrict__ enc16,
                            unsigned short* __restrict__ me16)
{
    int d = blockIdx.x * 256 + threadIdx.x;
    int b = blockIdx.y;
    const unsigned short* p = enc16 + (size_t)b * NPIX * ENCD + d;
    float s = 0.0f;
    for (int q = 0; q < NPIX; ++q) s += bf2f(p[(size_t)q * ENCD]);
    me16[b * ENCD + d] = f2bf(s * (1.0f / 196.0f));
}

// split hc0[64][1024] -> hh0 (bf16) and c (fp32)
__global__ void inithc_fin(const float* __restrict__ hc0,
                           unsigned short* __restrict__ hh0, float* __restrict__ c)
{
    int idx = blockIdx.x * 256 + threadIdx.x;  // 0..32767
    int b = idx >> 9, j = idx & 511;
    hh0[idx] = f2bf(hc0[(size_t)b * 1024 + j]);
    c[idx] = hc0[(size_t)b * 1024 + 512 + j];
}

__global__ void copy_misc(const int* __restrict__ caps, const int* __restrict__ lens,
                          float* __restrict__ out)
{
    int i = blockIdx.x * 256 + threadIdx.x;
    if (i < CAPS_SZ) out[PRED_SZ + i] = (float)caps[i];
    else if (i < CAPS_SZ + LENS_SZ) out[PRED_SZ + i] = (float)(lens[i - CAPS_SZ] - 1);
}

// ---------------------------------------------------------------------------
// Setup attenc GEMM: attenc16 = enc16 @ W_enc_att + b  (M=12544, N=512, K=2048)
// 128x128 tiles, grid (4, 98).
// ---------------------------------------------------------------------------
__global__ __launch_bounds__(256) void encatt_gemm(
    const unsigned short* __restrict__ A,
    const unsigned short* __restrict__ Wp,
    const float* __restrict__ bias,
    unsigned short* __restrict__ C16)
{
    const int n0 = blockIdx.x * 128;
    const int m0 = blockIdx.y * 128;
    const int w  = threadIdx.x >> 6;
    const int l  = threadIdx.x & 63;
    const int lr = l & 15;
    const int q  = l >> 4;

    const unsigned short* ap = A + (size_t)(m0 + 16 * w + lr) * 2048 + q * 8;
    const unsigned short* bp = Wp + (size_t)(n0 + lr) * 32 + q * 8;
    const size_t bstep = (size_t)512 * 32;

    f32x4 acc[16];
#pragma unroll
    for (int i = 0; i < 16; ++i) acc[i] = (f32x4){0.f, 0.f, 0.f, 0.f};

    short8 a0 = *(const short8*)(ap);
    short8 a1 = *(const short8*)(ap + 64 * 2048);
    short8 b[8];
#pragma unroll
    for (int nt = 0; nt < 8; ++nt) b[nt] = *(const short8*)(bp + nt * 512);

    for (int kb = 0; kb < 64; ++kb) {
        const size_t nxt = (kb + 1 < 64) ? 1 : 0;
        const unsigned short* apn = ap + nxt * 32;
        const unsigned short* bpn = bp + nxt * bstep;
        short8 an0 = *(const short8*)(apn);
        short8 an1 = *(const short8*)(apn + 64 * 2048);
        short8 bn[8];
#pragma unroll
        for (int nt = 0; nt < 8; ++nt) bn[nt] = *(const short8*)(bpn + nt * 512);
#pragma unroll
        for (int nt = 0; nt < 8; ++nt) {
            acc[nt]     = __builtin_amdgcn_mfma_f32_16x16x32_bf16(a0, b[nt], acc[nt], 0, 0, 0);
            acc[8 + nt] = __builtin_amdgcn_mfma_f32_16x16x32_bf16(a1, b[nt], acc[8 + nt], 0, 0, 0);
        }
        a0 = an0; a1 = an1;
#pragma unroll
        for (int nt = 0; nt < 8; ++nt) b[nt] = bn[nt];
        ap = apn; bp = bpn;
    }

    const int r0 = q * 4;
#pragma unroll
    for (int mt = 0; mt < 2; ++mt) {
#pragma unroll
        for (int nt = 0; nt < 8; ++nt) {
            int col = n0 + nt * 16 + lr;
            float bv = bias[col];
#pragma unroll
            for (int r = 0; r < 4; ++r) {
                int row = m0 + mt * 64 + 16 * w + r0 + r;
                C16[(size_t)row * 512 + col] = f2bf(acc[mt * 8 + nt][r] + bv);
            }
        }
    }
}

// ---------------------------------------------------------------------------
extern "C" void kernel_launch(void* const* d_in, const int* in_sizes, int n_in,
                              void* d_out, int out_size, void* d_ws, size_t ws_size,
                              hipStream_t stream)
{
    (void)in_sizes; (void)n_in; (void)out_size; (void)ws_size;
    const float* enc        = (const float*)d_in[0];
    const int*   caps       = (const int*)d_in[1];
    const int*   lens       = (const int*)d_in[2];
    const float* emb        = (const float*)d_in[3];
    const float* W_enc_att  = (const float*)d_in[4];
    const float* b_enc_att  = (const float*)d_in[5];
    const float* W_dec_att  = (const float*)d_in[6];
    const float* b_dec_att  = (const float*)d_in[7];
    const float* W_full_att = (const float*)d_in[8];
    const float* b_full_att = (const float*)d_in[9];
    const float* W_init_h   = (const float*)d_in[10];
    const float* b_init_h   = (const float*)d_in[11];
    const float* W_init_c   = (const float*)d_in[12];
    const float* b_init_c   = (const float*)d_in[13];
    const float* W_fbeta    = (const float*)d_in[14];
    const float* b_fbeta    = (const float*)d_in[15];
    const float* W_ih       = (const float*)d_in[16];
    const float* W_hh       = (const float*)d_in[17];
    const float* b_ih       = (const float*)d_in[18];
    const float* b_hh       = (const float*)d_in[19];
    const float* W_fc       = (const float*)d_in[20];
    const float* b_fc       = (const float*)d_in[21];
    float* out = (float*)d_out;

    // ---- workspace carve-up ----
    char* p = (char*)d_ws;
    unsigned short* enc16   = (unsigned short*)p; p += (size_t)BB * NPIX * ENCD * 2;   // 51.4MB
    unsigned short* attenc16= (unsigned short*)p; p += (size_t)BB * NPIX * 512 * 2;    // 12.8MB
    unsigned short* WpLi    = (unsigned short*)p; p += (size_t)96 * 2048 * 32 * 2;     // 12.6MB gates (interleaved) K=3072
    unsigned short* WpG     = (unsigned short*)p; p += (size_t)16 * 2560 * 32 * 2;     // 2.6MB  fbeta|dec_att K=512
    unsigned short* WpF     = (unsigned short*)p; p += (size_t)16 * NPADFC * 32 * 2;   // 10.3MB fc K=512
    unsigned short* WpE     = (unsigned short*)p; p += (size_t)64 * 512 * 32 * 2;      // 2.1MB  enc_att K=2048
    unsigned short* WpI     = (unsigned short*)p; p += (size_t)64 * 1024 * 32 * 2;     // 4.2MB  init_h|init_c K=2048
    unsigned short* xcatEG  = (unsigned short*)p; p += (size_t)BB * 2560 * 2;          // 320KB
    unsigned short* hh      = (unsigned short*)p; p += (size_t)(TT + 1) * BB * 512 * 2;// 3.4MB  h(0)..h(TT)
    unsigned short* me16    = (unsigned short*)p; p += (size_t)BB * ENCD * 2;          // 256KB
    float* gadec  = (float*)p; p += (size_t)BB * 2560 * 4;                             // 640KB
    float* hc0    = (float*)p; p += (size_t)BB * 1024 * 4;                             // 256KB
    float* c      = (float*)p; p += (size_t)BB * 512 * 4;                              // 128KB
    float* bcat   = (float*)p; p += 2560 * 4;
    float* bsum   = (float*)p; p += 2048 * 4;
    float* bcatI  = (float*)p; p += 1024 * 4;
    int*   flags  = (int*)p;  p += 64 * 4;

    // ---- setup ----
    {
        int n = BB * NPIX * ENCD;
        cast_kernel<<<(n / 4 + 255) / 256, 256, 0, stream>>>(enc, enc16, n);
    }
    { int tot = 96 * 2048 * 32;
      packGi_kernel<<<(tot + 255) / 256, 256, 0, stream>>>(W_ih, W_hh, WpLi, tot); }
    { int tot = 16 * 2560 * 32;
      pack_kernel<<<(tot + 255) / 256, 256, 0, stream>>>(W_fbeta, W_dec_att, 2048, 512, 0, 2560, 1, WpG, tot); }
    { int tot = 16 * NPADFC * 32;
      pack_kernel<<<(tot + 255) / 256, 256, 0, stream>>>(W_fc, nullptr, VOCAB_N, 0, 0, NPADFC, 0, WpF, tot); }
    { int tot = 64 * 512 * 32;
      pack_kernel<<<(tot + 255) / 256, 256, 0, stream>>>(W_enc_att, nullptr, 512, 0, 0, 512, 0, WpE, tot); }
    { int tot = 64 * 1024 * 32;
      pack_kernel<<<(tot + 255) / 256, 256, 0, stream>>>(W_init_h, W_init_c, 512, 512, 0, 1024, 1, WpI, tot); }
    bias_prep<<<15, 256, 0, stream>>>(b_fbeta, b_dec_att, b_ih, b_hh, b_init_h, b_init_c,
                                      bcat, bsum, bcatI, flags);
    mean_kernel<<<dim3(8, 64), 256, 0, stream>>>(enc16, me16);
    // hc0 = me16 @ [W_init_h | W_init_c] + [bh|bc]  (MFMA, 16 blocks)
    gemm_mfma<<<dim3(16, 1, 1), 256, 0, stream>>>(
        me16, 2048, WpI, 1024, 64, 0, hc0, nullptr, 1024,
        bcatI, 1024, 0, nullptr, 0);
    inithc_fin<<<128, 256, 0, stream>>>(hc0, hh, c);
    encatt_gemm<<<dim3(4, 98), 256, 0, stream>>>(enc16, WpE, b_enc_att, attenc16);
    copy_misc<<<14, 256, 0, stream>>>(caps, lens, out);

    // ---- decode loop: 2 kernels/step (fused gadec+attawe, then gates+lstm) ----
    for (int t = 0; t < TT; ++t) {
        fusedstep_kernel<<<168, 512, 0, stream>>>(
            hh + (size_t)t * BB * 512, WpG, bcat, gadec,
            attenc16, enc16, W_full_att, b_full_att,
            emb, caps, lens, t, xcatEG, out + ALPHAS_OFF, flags + t);
        gateslstm_kernel<<<128, 256, 0, stream>>>(
            xcatEG, hh + (size_t)t * BB * 512, WpLi, bsum, lens, t,
            c, hh + (size_t)(t + 1) * BB * 512);
    }

    // ---- all preds in one big GEMM over hh[1..TT] ----
    preds_gemm<<<dim3(160, 26), 256, 0, stream>>>(hh + (size_t)BB * 512, WpF, b_fc, lens, out);
}

// Round 12
// 3095.822 us; speedup vs baseline: 1.4173x; 1.4173x over previous
//
#include <hip/hip_runtime.h>
#include <hip/hip_bf16.h>
#include <math.h>

#define BB 64
#define NPIX 196
#define ENCD 2048
#define DECD 512
#define VOCAB_N 10000
#define MAXLEN 52
#define TT 51
#define NPADFC 10048

// Output layout (floats): preds | captions | declens | alphas
#define PRED_SZ   (BB * TT * VOCAB_N)
#define CAPS_SZ   (BB * MAXLEN)
#define LENS_SZ   (BB)
#define ALPHAS_OFF (PRED_SZ + CAPS_SZ + LENS_SZ)

typedef __attribute__((ext_vector_type(8))) short short8;
typedef __attribute__((ext_vector_type(4))) short short4v;
typedef __attribute__((ext_vector_type(4))) float f32x4;

__device__ __forceinline__ float fsigm(float x) {
    return 1.0f / (1.0f + __expf(-x));
}
__device__ __forceinline__ float ftanh(float x) {
    x = fminf(fmaxf(x, -15.0f), 15.0f);
    float e = __expf(2.0f * x);
    return (e - 1.0f) / (e + 1.0f);
}
__device__ __forceinline__ float bf2f(unsigned short u) {
    union { unsigned int i; float f; } v;
    v.i = ((unsigned int)u) << 16;
    return v.f;
}
__device__ __forceinline__ unsigned short f2bf(float f) {
    union { float f; unsigned int i; } v;
    v.f = f;
    unsigned int r = v.i + 0x7FFFu + ((v.i >> 16) & 1u);
    return (unsigned short)(r >> 16);
}

// ---------------------------------------------------------------------------
// Generic MFMA GEMM (verified). Used for in-loop gadec (40 blocks, act=2)
// and the setup inithc GEMM (16 blocks, act=0).
// ---------------------------------------------------------------------------
__global__ __launch_bounds__(256) void gemm_mfma(
    const unsigned short* __restrict__ A, int lda,
    const unsigned short* __restrict__ Wp, int Npad,
    int nkb, long slice_stride,
    float* __restrict__ C, unsigned short* __restrict__ C16, long ldc,
    const float* __restrict__ bias, int N, int act,
    const int* __restrict__ caplen, int t)
{
    const int n0 = blockIdx.x * 64;
    const int m0 = blockIdx.y * 64;
    const int kz = blockIdx.z;
    A  += (size_t)kz * nkb * 32;
    Wp += (size_t)kz * nkb * Npad * 32;
    if (C) C += (size_t)kz * slice_stride;

    const int w  = threadIdx.x >> 6;
    const int l  = threadIdx.x & 63;
    const int lr = l & 15;
    const int q  = l >> 4;

    const unsigned short* ap = A + (size_t)(m0 + 16 * w + lr) * lda + q * 8;
    const unsigned short* bp = Wp + (size_t)(n0 + lr) * 32 + q * 8;
    const size_t bstep = (size_t)Npad * 32;

    f32x4 acc[4];
#pragma unroll
    for (int i = 0; i < 4; ++i) acc[i] = (f32x4){0.f, 0.f, 0.f, 0.f};

    short8 a  = *(const short8*)ap;
    short8 b0 = *(const short8*)(bp);
    short8 b1 = *(const short8*)(bp + 512);
    short8 b2 = *(const short8*)(bp + 1024);
    short8 b3 = *(const short8*)(bp + 1536);

    for (int kb = 0; kb < nkb; ++kb) {
        const size_t nxt = (kb + 1 < nkb) ? 1 : 0;
        const unsigned short* apn = ap + nxt * 32;
        const unsigned short* bpn = bp + nxt * bstep;
        short8 an  = *(const short8*)apn;
        short8 bn0 = *(const short8*)(bpn);
        short8 bn1 = *(const short8*)(bpn + 512);
        short8 bn2 = *(const short8*)(bpn + 1024);
        short8 bn3 = *(const short8*)(bpn + 1536);
        acc[0] = __builtin_amdgcn_mfma_f32_16x16x32_bf16(a, b0, acc[0], 0, 0, 0);
        acc[1] = __builtin_amdgcn_mfma_f32_16x16x32_bf16(a, b1, acc[1], 0, 0, 0);
        acc[2] = __builtin_amdgcn_mfma_f32_16x16x32_bf16(a, b2, acc[2], 0, 0, 0);
        acc[3] = __builtin_amdgcn_mfma_f32_16x16x32_bf16(a, b3, acc[3], 0, 0, 0);
        a = an; b0 = bn0; b1 = bn1; b2 = bn2; b3 = bn3;
        ap = apn; bp = bpn;
    }

    const int r0 = q * 4;
#pragma unroll
    for (int cf = 0; cf < 4; ++cf) {
        int col = n0 + cf * 16 + lr;
        if (col >= N) continue;
        float bv = bias ? bias[col] : 0.f;
#pragma unroll
        for (int r = 0; r < 4; ++r) {
            int row = m0 + 16 * w + r0 + r;
            float v = acc[cf][r] + bv;
            if (act == 1 || (act == 2 && col < 2048)) v = fsigm(v);
            if (caplen) v *= (t < caplen[row] - 1) ? 1.f : 0.f;
            if (C16) C16[(size_t)row * ldc + col] = f2bf(v);
            else     C [(size_t)row * ldc + col] = v;
        }
    }
}

// ---------------------------------------------------------------------------
// Fused gates GEMM + LSTM (verified). 128 blocks (4m x 32n) x 256 thr.
// A operand: cols [0,2560) from xcatEG (bf16), [2560,3072) from hprev.
// ---------------------------------------------------------------------------
__global__ __launch_bounds__(256) void gateslstm_kernel(
    const unsigned short* __restrict__ xcatEG,   // [64][2560] emb|gate*awe
    const unsigned short* __restrict__ hprev,    // [64][512]
    const unsigned short* __restrict__ WpLi,
    const float* __restrict__ bsum,
    const int* __restrict__ caplen, int t,
    float* __restrict__ c,
    unsigned short* __restrict__ hnext)          // [64][512]
{
    __shared__ float gt[4][16][68];

    const int bx = blockIdx.x;
    const int nx = bx & 31;
    const int my = bx >> 5;
    const int m0 = my * 16;
    const int n0 = nx * 64;
    const int tid = threadIdx.x;
    const int ws = tid >> 6;       // wave = K-slice (768 each)
    const int l  = tid & 63;
    const int lr = l & 15;
    const int q  = l >> 4;

    const unsigned short* arow_x = xcatEG + (size_t)(m0 + lr) * 2560;
    const unsigned short* arow_h = hprev  + (size_t)(m0 + lr) * 512;
    const int kbase = ws * 768 + q * 8;

    const unsigned short* bp = WpLi + ((size_t)(ws * 24) * 2048 + n0 + lr) * 32 + q * 8;
    const size_t bstep = (size_t)2048 * 32;

    f32x4 acc[4];
#pragma unroll
    for (int i = 0; i < 4; ++i) acc[i] = (f32x4){0.f, 0.f, 0.f, 0.f};

#define ALOAD(kb) ({ int k0_ = kbase + (kb) * 32; \
    (k0_ < 2560) ? *(const short8*)(arow_x + k0_) \
                 : *(const short8*)(arow_h + (k0_ - 2560)); })

    short8 a  = ALOAD(0);
    short8 b0 = *(const short8*)(bp);
    short8 b1 = *(const short8*)(bp + 512);
    short8 b2 = *(const short8*)(bp + 1024);
    short8 b3 = *(const short8*)(bp + 1536);

    for (int kb = 0; kb < 24; ++kb) {
        const int kn = (kb + 1 < 24) ? kb + 1 : kb;
        const unsigned short* bpn = bp + ((kb + 1 < 24) ? bstep : 0);
        short8 an  = ALOAD(kn);
        short8 bn0 = *(const short8*)(bpn);
        short8 bn1 = *(const short8*)(bpn + 512);
        short8 bn2 = *(const short8*)(bpn + 1024);
        short8 bn3 = *(const short8*)(bpn + 1536);
        acc[0] = __builtin_amdgcn_mfma_f32_16x16x32_bf16(a, b0, acc[0], 0, 0, 0);
        acc[1] = __builtin_amdgcn_mfma_f32_16x16x32_bf16(a, b1, acc[1], 0, 0, 0);
        acc[2] = __builtin_amdgcn_mfma_f32_16x16x32_bf16(a, b2, acc[2], 0, 0, 0);
        acc[3] = __builtin_amdgcn_mfma_f32_16x16x32_bf16(a, b3, acc[3], 0, 0, 0);
        a = an; b0 = bn0; b1 = bn1; b2 = bn2; b3 = bn3;
        bp = bpn;
    }
#undef ALOAD

    const int r0 = q * 4;
#pragma unroll
    for (int cf = 0; cf < 4; ++cf)
#pragma unroll
        for (int r = 0; r < 4; ++r)
            gt[ws][r0 + r][cf * 16 + lr] = acc[cf][r];
    __syncthreads();

    // LSTM epilogue: 256 threads -> (row, unit) pairs, 16x16
    const int row = tid & 15;
    const int jj  = tid >> 4;
    const int b   = m0 + row;
    const int j   = nx * 16 + jj;
    const int lc  = 4 * jj;
    float gi = bsum[j],        gf = bsum[512 + j];
    float gg = bsum[1024 + j], go = bsum[1536 + j];
#pragma unroll
    for (int s = 0; s < 4; ++s) {
        gi += gt[s][row][lc + 0];
        gf += gt[s][row][lc + 1];
        gg += gt[s][row][lc + 2];
        go += gt[s][row][lc + 3];
    }
    const int cidx = b * 512 + j;
    float cn = fsigm(gf) * c[cidx] + fsigm(gi) * ftanh(gg);
    float hn = fsigm(go) * ftanh(cn);
    bool upd = (t < caplen[b] - 1);
    if (upd) c[cidx] = cn;
    hnext[cidx] = upd ? f2bf(hn) : hprev[cidx];
}

// ---------------------------------------------------------------------------
// Attention + awe + xcat build. 256 blocks x 512 thr: b = bx&63, dq = bx>>6.
// All 4 blocks of a row compute e+softmax redundantly (deterministic, same
// inputs); dq==0 writes alphas/emb; each block computes awe for its 512-dim
// quarter with 256 threads x 2 dims (4B loads; per-dim fp32 sum over all 196
// pixels -> bit-identical to unsplit). Quarter-split halves the per-block
// enc16 stream vs the round-7 half-split (awe was per-block-BW-bound).
// ---------------------------------------------------------------------------
__global__ __launch_bounds__(512) void attawe_kernel(
    const float* __restrict__ gadec,
    const unsigned short* __restrict__ attenc16,
    const unsigned short* __restrict__ enc16,
    const float* __restrict__ Wf, const float* __restrict__ bf_,
    const float* __restrict__ emb, const int* __restrict__ caps,
    const int* __restrict__ caplen, int t,
    unsigned short* __restrict__ xcatEG,
    float* __restrict__ alphas_out)
{
    int b  = blockIdx.x & 63;
    int dq = blockIdx.x >> 6;
    int tid = threadIdx.x;
    int lane = tid & 63, wid = tid >> 6;
    __shared__ float av[512];
    __shared__ float wv[512];
    __shared__ float es[NPIX];
    __shared__ float alpha_s[NPIX];
    __shared__ float r8[8];
    __shared__ float smax, ssum;

    av[tid] = gadec[(size_t)b * 2560 + 2048 + tid];
    wv[tid] = Wf[tid];
    __syncthreads();

    float mya[8], myw[8];
#pragma unroll
    for (int i = 0; i < 8; ++i) {
        mya[i] = av[lane * 8 + i];
        myw[i] = wv[lane * 8 + i];
    }

    float bf0 = bf_[0];
    for (int p = wid; p < NPIX; p += 8) {
        const unsigned short* ae = attenc16 + ((size_t)(b * NPIX + p)) * 512 + lane * 8;
        short8 e8 = *(const short8*)ae;
        float s = 0.f;
#pragma unroll
        for (int i = 0; i < 8; ++i)
            s += ftanh(bf2f((unsigned short)e8[i]) + mya[i]) * myw[i];
        for (int off = 32; off; off >>= 1) s += __shfl_down(s, off);
        if (lane == 0) es[p] = s + bf0;
    }
    __syncthreads();

    float v = (tid < NPIX) ? es[tid] : -1e30f;
    float m = v;
    for (int off = 32; off; off >>= 1) m = fmaxf(m, __shfl_down(m, off));
    if (lane == 0) r8[wid] = m;
    __syncthreads();
    if (tid == 0) {
        float mm = r8[0];
#pragma unroll
        for (int i = 1; i < 8; ++i) mm = fmaxf(mm, r8[i]);
        smax = mm;
    }
    __syncthreads();

    float ev = (tid < NPIX) ? __expf(v - smax) : 0.0f;
    float s = ev;
    for (int off = 32; off; off >>= 1) s += __shfl_down(s, off);
    if (lane == 0) r8[wid] = s;
    __syncthreads();
    if (tid == 0) {
        float ss = 0.f;
#pragma unroll
        for (int i = 0; i < 8; ++i) ss += r8[i];
        ssum = ss;
    }
    __syncthreads();

    float mk = (t < caplen[b] - 1) ? 1.0f : 0.0f;
    if (tid < NPIX) {
        float a = ev / ssum;
        alpha_s[tid] = a;
        if (dq == 0)
            alphas_out[((size_t)b * TT + t) * NPIX + tid] = a * mk;
    }
    __syncthreads();

    unsigned short* xr = xcatEG + (size_t)b * 2560;

    // awe: this block's 512-dim quarter, 256 threads x 2 dims (4B loads)
    if (tid < 256) {
        int d0 = dq * 512 + tid * 2;
        const unsigned short* e = enc16 + (size_t)b * NPIX * ENCD + d0;
        float s0 = 0.f, s1 = 0.f;
        for (int p = 0; p < NPIX; ++p) {
            unsigned int vv = *(const unsigned int*)(e + (size_t)p * ENCD);
            float a = alpha_s[p];
            s0 += a * bf2f((unsigned short)(vv & 0xffffu));
            s1 += a * bf2f((unsigned short)(vv >> 16));
        }
        const float* gtt = gadec + (size_t)b * 2560 + d0;
        xr[512 + d0 + 0] = f2bf(s0 * gtt[0]);
        xr[512 + d0 + 1] = f2bf(s1 * gtt[1]);
    }

    if (dq == 0) {
        int wword = caps[b * MAXLEN + t];
        xr[tid] = f2bf(emb[(size_t)wword * 512 + tid]);
    }
}

// ---------------------------------------------------------------------------
// Final preds GEMM over hh[1..TT]: rows = t*64+b (3264), K=512.
// Grid (160, 26): XCD-pinned n-tiles; 2 m-tiles/block (B-fragment reuse).
// Epilogue stages each 64x64 tile through LDS and stores float4 per lane.
// ---------------------------------------------------------------------------
__global__ __launch_bounds__(256) void preds_gemm(
    const unsigned short* __restrict__ hhist,   // = hh + 64*512
    const unsigned short* __restrict__ WpF,
    const float* __restrict__ bfc,
    const int* __restrict__ caplen,
    float* __restrict__ out)
{
    if (blockIdx.x >= 157) return;
    __shared__ float ot[64][68];
    const int n0 = blockIdx.x * 64;
    const int row0 = blockIdx.y * 128;
    const bool two = (row0 + 128 <= TT * BB);
    const int w  = threadIdx.x >> 6;
    const int l  = threadIdx.x & 63;
    const int lr = l & 15;
    const int q  = l >> 4;

    const unsigned short* ap0 = hhist + (size_t)(row0 + 16 * w + lr) * 512 + q * 8;
    const unsigned short* ap1 = ap0 + (size_t)64 * 512;
    const unsigned short* bp = WpF + (size_t)(n0 + lr) * 32 + q * 8;
    const size_t bstep = (size_t)NPADFC * 32;

    f32x4 acc[4], acc2[4];
#pragma unroll
    for (int i = 0; i < 4; ++i) {
        acc[i]  = (f32x4){0.f, 0.f, 0.f, 0.f};
        acc2[i] = (f32x4){0.f, 0.f, 0.f, 0.f};
    }

    short8 a0 = *(const short8*)ap0;
    short8 a1 = two ? *(const short8*)ap1 : a0;
    short8 b0 = *(const short8*)(bp);
    short8 b1 = *(const short8*)(bp + 512);
    short8 b2 = *(const short8*)(bp + 1024);
    short8 b3 = *(const short8*)(bp + 1536);

    for (int kb = 0; kb < 16; ++kb) {
        const size_t nxt = (kb + 1 < 16) ? 1 : 0;
        const unsigned short* apn0 = ap0 + nxt * 32;
        const unsigned short* apn1 = ap1 + nxt * 32;
        const unsigned short* bpn = bp + nxt * bstep;
        short8 an0 = *(const short8*)apn0;
        short8 an1 = two ? *(const short8*)apn1 : an0;
        short8 bn0 = *(const short8*)(bpn);
        short8 bn1 = *(const short8*)(bpn + 512);
        short8 bn2 = *(const short8*)(bpn + 1024);
        short8 bn3 = *(const short8*)(bpn + 1536);
        acc[0]  = __builtin_amdgcn_mfma_f32_16x16x32_bf16(a0, b0, acc[0], 0, 0, 0);
        acc[1]  = __builtin_amdgcn_mfma_f32_16x16x32_bf16(a0, b1, acc[1], 0, 0, 0);
        acc[2]  = __builtin_amdgcn_mfma_f32_16x16x32_bf16(a0, b2, acc[2], 0, 0, 0);
        acc[3]  = __builtin_amdgcn_mfma_f32_16x16x32_bf16(a0, b3, acc[3], 0, 0, 0);
        acc2[0] = __builtin_amdgcn_mfma_f32_16x16x32_bf16(a1, b0, acc2[0], 0, 0, 0);
        acc2[1] = __builtin_amdgcn_mfma_f32_16x16x32_bf16(a1, b1, acc2[1], 0, 0, 0);
        acc2[2] = __builtin_amdgcn_mfma_f32_16x16x32_bf16(a1, b2, acc2[2], 0, 0, 0);
        acc2[3] = __builtin_amdgcn_mfma_f32_16x16x32_bf16(a1, b3, acc2[3], 0, 0, 0);
        a0 = an0; a1 = an1; b0 = bn0; b1 = bn1; b2 = bn2; b3 = bn3;
        ap0 = apn0; ap1 = apn1; bp = bpn;
    }

    const int r0 = q * 4;
    const int colg = threadIdx.x & 15;   // 16 groups of 4 cols
    const int rowi = threadIdx.x >> 4;   // 16 rows per pass
    const int cbase = n0 + colg * 4;

#pragma unroll
    for (int mt = 0; mt < 2; ++mt) {
        if (mt == 1 && !two) break;
#pragma unroll
        for (int cf = 0; cf < 4; ++cf)
#pragma unroll
            for (int r = 0; r < 4; ++r)
                ot[16 * w + r0 + r][cf * 16 + lr] = mt ? acc2[cf][r] : acc[cf][r];
        __syncthreads();

#pragma unroll
        for (int ps = 0; ps < 4; ++ps) {
            int lrow = ps * 16 + rowi;
            int row = row0 + mt * 64 + lrow;
            int tt = row >> 6, b = row & 63;
            float mk = (tt < caplen[b] - 1) ? 1.f : 0.f;
            float4 v;
            v.x = (ot[lrow][colg * 4 + 0] + bfc[cbase + 0]) * mk;
            v.y = (ot[lrow][colg * 4 + 1] + bfc[cbase + 1]) * mk;
            v.z = (ot[lrow][colg * 4 + 2] + bfc[cbase + 2]) * mk;
            v.w = (ot[lrow][colg * 4 + 3] + bfc[cbase + 3]) * mk;
            float* o = out + ((size_t)b * TT + tt) * VOCAB_N + cbase;
            if (cbase + 3 < VOCAB_N) {
                *(float4*)o = v;
            } else {
                if (cbase + 0 < VOCAB_N) o[0] = v.x;
                if (cbase + 1 < VOCAB_N) o[1] = v.y;
                if (cbase + 2 < VOCAB_N) o[2] = v.z;
                if (cbase + 3 < VOCAB_N) o[3] = v.w;
            }
        }
        __syncthreads();
    }
}

// ---------------------------------------------------------------------------
// Weight packing: Wp[(kb*Npad + n)*32 + kk] = src[k=kb*32+kk][n], bf16.
// mode 0: single source; mode 1: n-concat [W1|W2].
// ---------------------------------------------------------------------------
__global__ void pack_kernel(const float* __restrict__ W1, const float* __restrict__ W2,
                            int N1, int N2, int K1, int Npad, int mode,
                            unsigned short* __restrict__ Wp, int total)
{
    int idx = blockIdx.x * 256 + threadIdx.x;
    if (idx >= total) return;
    int kk = idx & 31;
    int r  = idx >> 5;
    int n  = r % Npad;
    int kb = r / Npad;
    int k  = kb * 32 + kk;
    float v = 0.f;
    if (mode == 0) {
        if (n < N1) v = W1[(size_t)k * N1 + n];
    } else if (mode == 1) {
        v = (n < N1) ? W1[(size_t)k * N1 + n] : W2[(size_t)k * N2 + (n - N1)];
    } else {
        v = (k < K1) ? W1[(size_t)k * N1 + n] : W2[(size_t)(k - K1) * N1 + n];
    }
    Wp[idx] = f2bf(v);
}

// gate-interleaved pack of [W_ih(2560x2048); W_hh(512x2048)]:
// packed col n -> original col (n&3)*512 + (n>>2)   (verified round 3)
__global__ void packGi_kernel(const float* __restrict__ Wih,
                              const float* __restrict__ Whh,
                              unsigned short* __restrict__ Wp, int total)
{
    int idx = blockIdx.x * 256 + threadIdx.x;
    if (idx >= total) return;
    int kk = idx & 31;
    int r  = idx >> 5;
    int n  = r % 2048;
    int kb = r / 2048;
    int k  = kb * 32 + kk;
    int oc = (n & 3) * 512 + (n >> 2);
    float v = (k < 2560) ? Wih[(size_t)k * 2048 + oc]
                         : Whh[(size_t)(k - 2560) * 2048 + oc];
    Wp[idx] = f2bf(v);
}

__global__ void cast_kernel(const float* __restrict__ src,
                            unsigned short* __restrict__ dst, int n)
{
    int i = (blockIdx.x * 256 + threadIdx.x) * 4;
    if (i >= n) return;
    float4 v = *(const float4*)(src + i);
    dst[i]     = f2bf(v.x);
    dst[i + 1] = f2bf(v.y);
    dst[i + 2] = f2bf(v.z);
    dst[i + 3] = f2bf(v.w);
}

// bcat[2560] = [b_fbeta | b_dec_att]; bsum[2048] = b_ih + b_hh;
// bcatI[1024] = [b_init_h | b_init_c]
__global__ void bias_prep(const float* __restrict__ bfb, const float* __restrict__ bda,
                          const float* __restrict__ bih, const float* __restrict__ bhh,
                          const float* __restrict__ bh, const float* __restrict__ bc,
                          float* __restrict__ bcat, float* __restrict__ bsum,
                          float* __restrict__ bcatI)
{
    int i = blockIdx.x * 256 + threadIdx.x;
    if (i < 2048) { bcat[i] = bfb[i]; bsum[i] = bih[i] + bhh[i]; }
    else if (i < 2560) bcat[i] = bda[i - 2048];
    else if (i < 3072) bcatI[i - 2560] = bh[i - 2560];
    else if (i < 3584) bcatI[i - 2560] = bc[i - 3072];
}

// mean over pixels, from enc16 (bf16), fp32 accum, bf16 out
__global__ void mean_kernel(const unsigned short* __restrict__ enc16,
                            unsigned short* __restrict__ me16)
{
    int d = blockIdx.x * 256 + threadIdx.x;
    int b = blockIdx.y;
    const unsigned short* p = enc16 + (size_t)b * NPIX * ENCD + d;
    float s = 0.0f;
    for (int q = 0; q < NPIX; ++q) s += bf2f(p[(size_t)q * ENCD]);
    me16[b * ENCD + d] = f2bf(s * (1.0f / 196.0f));
}

// split hc0[64][1024] -> hh0 (bf16) and c (fp32)
__global__ void inithc_fin(const float* __restrict__ hc0,
                           unsigned short* __restrict__ hh0, float* __restrict__ c)
{
    int idx = blockIdx.x * 256 + threadIdx.x;  // 0..32767
    int b = idx >> 9, j = idx & 511;
    hh0[idx] = f2bf(hc0[(size_t)b * 1024 + j]);
    c[idx] = hc0[(size_t)b * 1024 + 512 + j];
}

__global__ void copy_misc(const int* __restrict__ caps, const int* __restrict__ lens,
                          float* __restrict__ out)
{
    int i = blockIdx.x * 256 + threadIdx.x;
    if (i < CAPS_SZ) out[PRED_SZ + i] = (float)caps[i];
    else if (i < CAPS_SZ + LENS_SZ) out[PRED_SZ + i] = (float)(lens[i - CAPS_SZ] - 1);
}

// ---------------------------------------------------------------------------
// Setup attenc GEMM: attenc16 = enc16 @ W_enc_att + b  (M=12544, N=512, K=2048)
// 128x128 tiles, grid (4, 98).
// ---------------------------------------------------------------------------
__global__ __launch_bounds__(256) void encatt_gemm(
    const unsigned short* __restrict__ A,
    const unsigned short* __restrict__ Wp,
    const float* __restrict__ bias,
    unsigned short* __restrict__ C16)
{
    const int n0 = blockIdx.x * 128;
    const int m0 = blockIdx.y * 128;
    const int w  = threadIdx.x >> 6;
    const int l  = threadIdx.x & 63;
    const int lr = l & 15;
    const int q  = l >> 4;

    const unsigned short* ap = A + (size_t)(m0 + 16 * w + lr) * 2048 + q * 8;
    const unsigned short* bp = Wp + (size_t)(n0 + lr) * 32 + q * 8;
    const size_t bstep = (size_t)512 * 32;

    f32x4 acc[16];
#pragma unroll
    for (int i = 0; i < 16; ++i) acc[i] = (f32x4){0.f, 0.f, 0.f, 0.f};

    short8 a0 = *(const short8*)(ap);
    short8 a1 = *(const short8*)(ap + 64 * 2048);
    short8 b[8];
#pragma unroll
    for (int nt = 0; nt < 8; ++nt) b[nt] = *(const short8*)(bp + nt * 512);

    for (int kb = 0; kb < 64; ++kb) {
        const size_t nxt = (kb + 1 < 64) ? 1 : 0;
        const unsigned short* apn = ap + nxt * 32;
        const unsigned short* bpn = bp + nxt * bstep;
        short8 an0 = *(const short8*)(apn);
        short8 an1 = *(const short8*)(apn + 64 * 2048);
        short8 bn[8];
#pragma unroll
        for (int nt = 0; nt < 8; ++nt) bn[nt] = *(const short8*)(bpn + nt * 512);
#pragma unroll
        for (int nt = 0; nt < 8; ++nt) {
            acc[nt]     = __builtin_amdgcn_mfma_f32_16x16x32_bf16(a0, b[nt], acc[nt], 0, 0, 0);
            acc[8 + nt] = __builtin_amdgcn_mfma_f32_16x16x32_bf16(a1, b[nt], acc[8 + nt], 0, 0, 0);
        }
        a0 = an0; a1 = an1;
#pragma unroll
        for (int nt = 0; nt < 8; ++nt) b[nt] = bn[nt];
        ap = apn; bp = bpn;
    }

    const int r0 = q * 4;
#pragma unroll
    for (int mt = 0; mt < 2; ++mt) {
#pragma unroll
        for (int nt = 0; nt < 8; ++nt) {
            int col = n0 + nt * 16 + lr;
            float bv = bias[col];
#pragma unroll
            for (int r = 0; r < 4; ++r) {
                int row = m0 + mt * 64 + 16 * w + r0 + r;
                C16[(size_t)row * 512 + col] = f2bf(acc[mt * 8 + nt][r] + bv);
            }
        }
    }
}

// ---------------------------------------------------------------------------
extern "C" void kernel_launch(void* const* d_in, const int* in_sizes, int n_in,
                              void* d_out, int out_size, void* d_ws, size_t ws_size,
                              hipStream_t stream)
{
    (void)in_sizes; (void)n_in; (void)out_size; (void)ws_size;
    const float* enc        = (const float*)d_in[0];
    const int*   caps       = (const int*)d_in[1];
    const int*   lens       = (const int*)d_in[2];
    const float* emb        = (const float*)d_in[3];
    const float* W_enc_att  = (const float*)d_in[4];
    const float* b_enc_att  = (const float*)d_in[5];
    const float* W_dec_att  = (const float*)d_in[6];
    const float* b_dec_att  = (const float*)d_in[7];
    const float* W_full_att = (const float*)d_in[8];
    const float* b_full_att = (const float*)d_in[9];
    const float* W_init_h   = (const float*)d_in[10];
    const float* b_init_h   = (const float*)d_in[11];
    const float* W_init_c   = (const float*)d_in[12];
    const float* b_init_c   = (const float*)d_in[13];
    const float* W_fbeta    = (const float*)d_in[14];
    const float* b_fbeta    = (const float*)d_in[15];
    const float* W_ih       = (const float*)d_in[16];
    const float* W_hh       = (const float*)d_in[17];
    const float* b_ih       = (const float*)d_in[18];
    const float* b_hh       = (const float*)d_in[19];
    const float* W_fc       = (const float*)d_in[20];
    const float* b_fc       = (const float*)d_in[21];
    float* out = (float*)d_out;

    // ---- workspace carve-up ----
    char* p = (char*)d_ws;
    unsigned short* enc16   = (unsigned short*)p; p += (size_t)BB * NPIX * ENCD * 2;   // 51.4MB
    unsigned short* attenc16= (unsigned short*)p; p += (size_t)BB * NPIX * 512 * 2;    // 12.8MB
    unsigned short* WpLi    = (unsigned short*)p; p += (size_t)96 * 2048 * 32 * 2;     // 12.6MB gates (interleaved) K=3072
    unsigned short* WpG     = (unsigned short*)p; p += (size_t)16 * 2560 * 32 * 2;     // 2.6MB  fbeta|dec_att K=512
    unsigned short* WpF     = (unsigned short*)p; p += (size_t)16 * NPADFC * 32 * 2;   // 10.3MB fc K=512
    unsigned short* WpE     = (unsigned short*)p; p += (size_t)64 * 512 * 32 * 2;      // 2.1MB  enc_att K=2048
    unsigned short* WpI     = (unsigned short*)p; p += (size_t)64 * 1024 * 32 * 2;     // 4.2MB  init_h|init_c K=2048
    unsigned short* xcatEG  = (unsigned short*)p; p += (size_t)BB * 2560 * 2;          // 320KB
    unsigned short* hh      = (unsigned short*)p; p += (size_t)(TT + 1) * BB * 512 * 2;// 3.4MB  h(0)..h(TT)
    unsigned short* me16    = (unsigned short*)p; p += (size_t)BB * ENCD * 2;          // 256KB
    float* gadec  = (float*)p; p += (size_t)BB * 2560 * 4;                             // 640KB
    float* hc0    = (float*)p; p += (size_t)BB * 1024 * 4;                             // 256KB
    float* c      = (float*)p; p += (size_t)BB * 512 * 4;                              // 128KB
    float* bcat   = (float*)p; p += 2560 * 4;
    float* bsum   = (float*)p; p += 2048 * 4;
    float* bcatI  = (float*)p; p += 1024 * 4;

    // ---- setup ----
    {
        int n = BB * NPIX * ENCD;
        cast_kernel<<<(n / 4 + 255) / 256, 256, 0, stream>>>(enc, enc16, n);
    }
    { int tot = 96 * 2048 * 32;
      packGi_kernel<<<(tot + 255) / 256, 256, 0, stream>>>(W_ih, W_hh, WpLi, tot); }
    { int tot = 16 * 2560 * 32;
      pack_kernel<<<(tot + 255) / 256, 256, 0, stream>>>(W_fbeta, W_dec_att, 2048, 512, 0, 2560, 1, WpG, tot); }
    { int tot = 16 * NPADFC * 32;
      pack_kernel<<<(tot + 255) / 256, 256, 0, stream>>>(W_fc, nullptr, VOCAB_N, 0, 0, NPADFC, 0, WpF, tot); }
    { int tot = 64 * 512 * 32;
      pack_kernel<<<(tot + 255) / 256, 256, 0, stream>>>(W_enc_att, nullptr, 512, 0, 0, 512, 0, WpE, tot); }
    { int tot = 64 * 1024 * 32;
      pack_kernel<<<(tot + 255) / 256, 256, 0, stream>>>(W_init_h, W_init_c, 512, 512, 0, 1024, 1, WpI, tot); }
    bias_prep<<<14, 256, 0, stream>>>(b_fbeta, b_dec_att, b_ih, b_hh, b_init_h, b_init_c,
                                      bcat, bsum, bcatI);
    mean_kernel<<<dim3(8, 64), 256, 0, stream>>>(enc16, me16);
    // hc0 = me16 @ [W_init_h | W_init_c] + [bh|bc]  (MFMA, 16 blocks)
    gemm_mfma<<<dim3(16, 1, 1), 256, 0, stream>>>(
        me16, 2048, WpI, 1024, 64, 0, hc0, nullptr, 1024,
        bcatI, 1024, 0, nullptr, 0);
    inithc_fin<<<128, 256, 0, stream>>>(hc0, hh, c);
    encatt_gemm<<<dim3(4, 98), 256, 0, stream>>>(enc16, WpE, b_enc_att, attenc16);
    copy_misc<<<14, 256, 0, stream>>>(caps, lens, out);

    // gadec(0) = [sigmoid(h0@Wfbeta+b) | h0@Wd+bd]
    gemm_mfma<<<dim3(40, 1, 1), 256, 0, stream>>>(
        hh, 512, WpG, 2560, 16, 0, gadec, nullptr, 2560,
        bcat, 2560, 2, nullptr, 0);

    // ---- decode loop: 3 kernels/step (2 on the last) ----
    for (int t = 0; t < TT; ++t) {
        attawe_kernel<<<256, 512, 0, stream>>>(
            gadec, attenc16, enc16, W_full_att, b_full_att,
            emb, caps, lens, t, xcatEG, out + ALPHAS_OFF);
        gateslstm_kernel<<<128, 256, 0, stream>>>(
            xcatEG, hh + (size_t)t * BB * 512, WpLi, bsum, lens, t,
            c, hh + (size_t)(t + 1) * BB * 512);
        if (t + 1 < TT) {
            gemm_mfma<<<dim3(40, 1, 1), 256, 0, stream>>>(
                hh + (size_t)(t + 1) * BB * 512, 512, WpG, 2560, 16, 0,
                gadec, nullptr, 2560, bcat, 2560, 2, nullptr, 0);
        }
    }

    // ---- all preds in one big GEMM over hh[1..TT] ----
    preds_gemm<<<dim3(160, 26), 256, 0, stream>>>(hh + (size_t)BB * 512, WpF, b_fc, lens, out);
}